// Round 1
// baseline (5521.216 us; speedup 1.0000x reference)
//
#include <hip/hip_runtime.h>

#define HDIM 128
#define BN_EPS 1e-5f

// ---------------- degree / norm ----------------
__global__ void k_init_deg(float* __restrict__ deg, int n) {
    int i = blockIdx.x * blockDim.x + threadIdx.x;
    if (i < n) deg[i] = 1.0f;   // self-loop
}

__global__ void k_deg_accum(const int* __restrict__ dst, float* __restrict__ deg, int e) {
    int i = blockIdx.x * blockDim.x + threadIdx.x;
    if (i < e) atomicAdd(&deg[dst[i]], 1.0f);
}

__global__ void k_rsqrt_inplace(float* __restrict__ d, int n) {
    int i = blockIdx.x * blockDim.x + threadIdx.x;
    if (i < n) d[i] = rsqrtf(d[i]);
}

// ---------------- layer-0 GEMM (K = F_IN = 11) ----------------
// hs = (x @ W) * dinv[row]; agg initialized with hs (self-loop term)
__global__ __launch_bounds__(256) void k_gemm0(
    const float* __restrict__ x, const float* __restrict__ W,
    const float* __restrict__ dinv, float* __restrict__ hs,
    float* __restrict__ agg, int n, int fin) {
    int row = blockIdx.x * 2 + (threadIdx.x >> 7);
    int f = threadIdx.x & 127;
    if (row >= n) return;
    float acc = 0.0f;
    for (int k = 0; k < fin; ++k)
        acc += x[row * fin + k] * W[k * HDIM + f];
    float v = acc * dinv[row];
    hs[row * HDIM + f] = v;
    agg[row * HDIM + f] = v;
}

// ---------------- main GEMM (128x128 weights), 64-row tile ----------------
__global__ __launch_bounds__(256) void k_gemm(
    const float* __restrict__ x, const float* __restrict__ W,
    const float* __restrict__ dinv, float* __restrict__ hs,
    float* __restrict__ agg, int n) {
    __shared__ float xs[64][HDIM];
    int row0 = blockIdx.x * 64;
    int tid = threadIdx.x;

    // cooperative load of 64x128 fp32 tile (2048 float4s, 8 per thread)
    #pragma unroll
    for (int j = 0; j < 8; ++j) {
        int fid = tid + 256 * j;     // float4 index
        int r = fid >> 5, k4 = fid & 31;
        float4 v = make_float4(0.f, 0.f, 0.f, 0.f);
        int gr = row0 + r;
        if (gr < n) v = *(const float4*)(x + (size_t)gr * HDIM + k4 * 4);
        *(float4*)(&xs[r][k4 * 4]) = v;
    }
    __syncthreads();

    int rg = tid >> 5;   // 0..7 -> rows rg*8 .. rg*8+7
    int cg = tid & 31;   // cols cg*4 .. cg*4+3
    float4 acc[8];
    #pragma unroll
    for (int r = 0; r < 8; ++r) acc[r] = make_float4(0.f, 0.f, 0.f, 0.f);

    for (int kk = 0; kk < HDIM; kk += 4) {
        float4 wv[4];
        #pragma unroll
        for (int k = 0; k < 4; ++k)
            wv[k] = *(const float4*)(W + (size_t)(kk + k) * HDIM + cg * 4);
        #pragma unroll
        for (int r = 0; r < 8; ++r) {
            float4 xv = *(const float4*)(&xs[rg * 8 + r][kk]);
            acc[r].x += xv.x * wv[0].x + xv.y * wv[1].x + xv.z * wv[2].x + xv.w * wv[3].x;
            acc[r].y += xv.x * wv[0].y + xv.y * wv[1].y + xv.z * wv[2].y + xv.w * wv[3].y;
            acc[r].z += xv.x * wv[0].z + xv.y * wv[1].z + xv.z * wv[2].z + xv.w * wv[3].z;
            acc[r].w += xv.x * wv[0].w + xv.y * wv[1].w + xv.z * wv[2].w + xv.w * wv[3].w;
        }
    }

    #pragma unroll
    for (int r = 0; r < 8; ++r) {
        int gr = row0 + rg * 8 + r;
        if (gr < n) {
            float s = dinv[gr];
            float4 o = make_float4(acc[r].x * s, acc[r].y * s, acc[r].z * s, acc[r].w * s);
            *(float4*)(hs + (size_t)gr * HDIM + cg * 4) = o;
            *(float4*)(agg + (size_t)gr * HDIM + cg * 4) = o;
        }
    }
}

// ---------------- edge scatter: agg[dst] += hs[src] ----------------
__global__ void k_scatter(const int* __restrict__ src, const int* __restrict__ dst,
                          const float* __restrict__ hs, float* __restrict__ agg, int e) {
    int t = blockIdx.x * blockDim.x + threadIdx.x;   // e*32 threads, float4 each
    if (t >= e * 32) return;
    int ed = t >> 5, f4 = (t & 31) * 4;
    int s = src[ed], d = dst[ed];
    float4 v = *(const float4*)(hs + (size_t)s * HDIM + f4);
    float* ap = agg + (size_t)d * HDIM + f4;
    atomicAdd(ap + 0, v.x);
    atomicAdd(ap + 1, v.y);
    atomicAdd(ap + 2, v.z);
    atomicAdd(ap + 3, v.w);
}

// ---------------- post: bias + BN(eval) + ReLU + residual ----------------
__global__ void k_post(const float* __restrict__ agg, const float* __restrict__ dinv,
                       const float* __restrict__ bias, const float* __restrict__ gamma,
                       const float* __restrict__ beta, const float* __restrict__ mean,
                       const float* __restrict__ var, const float* __restrict__ xold,
                       float* __restrict__ xnew, int n, int use_res) {
    int t = blockIdx.x * blockDim.x + threadIdx.x;
    if (t >= n * 32) return;
    int row = t >> 5, f4 = (t & 31) * 4;
    float di = dinv[row];
    float4 a = *(const float4*)(agg + (size_t)row * HDIM + f4);
    float4 bv = *(const float4*)(bias + f4);
    float4 gv = *(const float4*)(gamma + f4);
    float4 be = *(const float4*)(beta + f4);
    float4 mv = *(const float4*)(mean + f4);
    float4 vv = *(const float4*)(var + f4);
    float4 o;
    o.x = fmaxf((di * a.x + bv.x - mv.x) * rsqrtf(vv.x + BN_EPS) * gv.x + be.x, 0.f);
    o.y = fmaxf((di * a.y + bv.y - mv.y) * rsqrtf(vv.y + BN_EPS) * gv.y + be.y, 0.f);
    o.z = fmaxf((di * a.z + bv.z - mv.z) * rsqrtf(vv.z + BN_EPS) * gv.z + be.z, 0.f);
    o.w = fmaxf((di * a.w + bv.w - mv.w) * rsqrtf(vv.w + BN_EPS) * gv.w + be.w, 0.f);
    if (use_res) {
        float4 xo = *(const float4*)(xold + (size_t)row * HDIM + f4);
        o.x += xo.x; o.y += xo.y; o.z += xo.z; o.w += xo.w;
    }
    *(float4*)(xnew + (size_t)row * HDIM + f4) = o;
}

// ---------------- pooling ----------------
__global__ void k_zero_pool(float* __restrict__ pooled, float* __restrict__ cnt, int g) {
    int t = blockIdx.x * blockDim.x + threadIdx.x;
    if (t < g * HDIM) pooled[t] = 0.f;
    if (t < g) cnt[t] = 0.f;
}

__global__ void k_pool(const float* __restrict__ x, const int* __restrict__ batch,
                       float* __restrict__ pooled, float* __restrict__ cnt, int n) {
    int t = blockIdx.x * blockDim.x + threadIdx.x;
    if (t >= n * 32) return;
    int row = t >> 5, f4 = (t & 31) * 4;
    int g = batch[row];
    float4 v = *(const float4*)(x + (size_t)row * HDIM + f4);
    float* p = pooled + (size_t)g * HDIM + f4;
    atomicAdd(p + 0, v.x);
    atomicAdd(p + 1, v.y);
    atomicAdd(p + 2, v.z);
    atomicAdd(p + 3, v.w);
    if ((t & 31) == 0) atomicAdd(&cnt[g], 1.0f);
}

// ---------------- head MLP: relu(pooled @ w1 + b1) @ w2 + b2 ----------------
__global__ __launch_bounds__(64) void k_head(
    const float* __restrict__ pooled, const float* __restrict__ cnt,
    const float* __restrict__ w1, const float* __restrict__ b1,
    const float* __restrict__ w2, const float* __restrict__ b2,
    float* __restrict__ out) {
    __shared__ float p[HDIM];
    int g = blockIdx.x;
    int t = threadIdx.x;
    float inv = 1.0f / fmaxf(cnt[g], 1.0f);
    p[t]      = pooled[(size_t)g * HDIM + t] * inv;
    p[t + 64] = pooled[(size_t)g * HDIM + 64 + t] * inv;
    __syncthreads();
    float h = b1[t];
    #pragma unroll 4
    for (int k = 0; k < HDIM; ++k)
        h += p[k] * w1[k * 64 + t];
    h = fmaxf(h, 0.f);
    float part = h * w2[t];
    #pragma unroll
    for (int off = 32; off > 0; off >>= 1)
        part += __shfl_down(part, off);
    if (t == 0) out[g] = part + b2[0];
}

extern "C" void kernel_launch(void* const* d_in, const int* in_sizes, int n_in,
                              void* d_out, int out_size, void* d_ws, size_t ws_size,
                              hipStream_t stream) {
    const float* x0   = (const float*)d_in[0];
    const int*   eidx = (const int*)  d_in[1];
    const int*   batch= (const int*)  d_in[2];
    const float* W0   = (const float*)d_in[3];
    const float* b0   = (const float*)d_in[4];
    const float* Ws   = (const float*)d_in[5];
    const float* bs   = (const float*)d_in[6];
    const float* gam  = (const float*)d_in[7];
    const float* bet  = (const float*)d_in[8];
    const float* mean = (const float*)d_in[9];
    const float* var  = (const float*)d_in[10];
    const float* w1   = (const float*)d_in[11];
    const float* b1   = (const float*)d_in[12];
    const float* w2   = (const float*)d_in[13];
    const float* b2   = (const float*)d_in[14];

    const int FIN = 11;
    int n = in_sizes[0] / FIN;      // 50000
    int e = in_sizes[1] / 2;        // 600000
    int g = out_size;               // 2048

    float* ws = (float*)d_ws;
    size_t nal = ((size_t)n + 63) & ~(size_t)63;
    size_t nh  = (size_t)n * HDIM;
    float* deg    = ws;                    // n (becomes dinv)
    float* bufA   = ws + nal;              // n*H
    float* bufB   = bufA + nh;             // n*H
    float* bufC   = bufB + nh;             // n*H (agg)
    float* pooled = bufC + nh;             // g*H
    float* cnt    = pooled + (size_t)g * HDIM;  // g

    const int* src = eidx;
    const int* dst = eidx + e;

    // degree + norm
    k_init_deg<<<(n + 255) / 256, 256, 0, stream>>>(deg, n);
    k_deg_accum<<<(e + 255) / 256, 256, 0, stream>>>(dst, deg, e);
    k_rsqrt_inplace<<<(n + 255) / 256, 256, 0, stream>>>(deg, n);

    // 5 GCN layers
    for (int i = 0; i < 5; ++i) {
        float* hb = (i & 1) ? bufB : bufA;            // hs, then x_out
        const float* xin = (i == 0) ? x0 : ((i & 1) ? bufA : bufB);
        const float* bias = (i == 0) ? b0 : bs + (size_t)(i - 1) * HDIM;
        if (i == 0) {
            k_gemm0<<<(n + 1) / 2, 256, 0, stream>>>(x0, W0, deg, hb, bufC, n, FIN);
        } else {
            const float* W = Ws + (size_t)(i - 1) * HDIM * HDIM;
            k_gemm<<<(n + 63) / 64, 256, 0, stream>>>(xin, W, deg, hb, bufC, n);
        }
        k_scatter<<<((size_t)e * 32 + 255) / 256, 256, 0, stream>>>(src, dst, hb, bufC, e);
        k_post<<<((size_t)n * 32 + 255) / 256, 256, 0, stream>>>(
            bufC, deg, bias, gam + i * HDIM, bet + i * HDIM, mean + i * HDIM,
            var + i * HDIM, xin, hb, n, (i > 0) ? 1 : 0);
    }

    // global mean pool (final x lives in bufA: layer 4 wrote hb = bufA)
    k_zero_pool<<<((size_t)g * HDIM + 255) / 256, 256, 0, stream>>>(pooled, cnt, g);
    k_pool<<<((size_t)n * 32 + 255) / 256, 256, 0, stream>>>(bufA, batch, pooled, cnt, n);
    k_head<<<g, 64, 0, stream>>>(pooled, cnt, w1, b1, w2, b2, (float*)d_out);
}

// Round 2
// 704.488 us; speedup vs baseline: 7.8372x; 7.8372x over previous
//
#include <hip/hip_runtime.h>

#define HDIM 128
#define BN_EPS 1e-5f

// ================= prologue: degree, dinv, CSR build =================

__global__ void k_zero2(int* __restrict__ a, int* __restrict__ b, int n) {
    int i = blockIdx.x * blockDim.x + threadIdx.x;
    if (i < n) { a[i] = 0; b[i] = 0; }
}

__global__ void k_deg_accum(const int* __restrict__ dst, int* __restrict__ deg, int e) {
    int i = blockIdx.x * blockDim.x + threadIdx.x;
    if (i < e) atomicAdd(&deg[dst[i]], 1);
}

__global__ void k_dinv(const int* __restrict__ deg, float* __restrict__ dinv, int n) {
    int i = blockIdx.x * blockDim.x + threadIdx.x;
    if (i < n) dinv[i] = rsqrtf((float)deg[i] + 1.0f);   // +1 self-loop
}

// exclusive scan of deg -> rs, 3-kernel hierarchical (n=50000 -> 196 blocks)
__global__ void k_scan1(const int* __restrict__ deg, int* __restrict__ rs,
                        int* __restrict__ blk, int n) {
    __shared__ int s[256];
    int i = blockIdx.x * 256 + threadIdx.x;
    int v = (i < n) ? deg[i] : 0;
    s[threadIdx.x] = v;
    __syncthreads();
    for (int off = 1; off < 256; off <<= 1) {
        int t = (threadIdx.x >= off) ? s[threadIdx.x - off] : 0;
        __syncthreads();
        s[threadIdx.x] += t;
        __syncthreads();
    }
    if (i < n) rs[i] = s[threadIdx.x] - v;               // exclusive
    if (threadIdx.x == 255) blk[blockIdx.x] = s[255];
}

__global__ void k_scan2(int* __restrict__ blk, int nb) {
    __shared__ int s[256];
    int t = threadIdx.x;
    int v = (t < nb) ? blk[t] : 0;
    s[t] = v;
    __syncthreads();
    for (int off = 1; off < 256; off <<= 1) {
        int u = (t >= off) ? s[t - off] : 0;
        __syncthreads();
        s[t] += u;
        __syncthreads();
    }
    if (t < nb) blk[t] = s[t] - v;                       // exclusive
}

__global__ void k_scan3(int* __restrict__ rs, const int* __restrict__ blk, int n) {
    int i = blockIdx.x * 256 + threadIdx.x;
    if (i < n) rs[i] += blk[blockIdx.x];
}

__global__ void k_fill(const int* __restrict__ src, const int* __restrict__ dst,
                       const int* __restrict__ rs, int* __restrict__ cur,
                       int* __restrict__ csr, int e) {
    int i = blockIdx.x * blockDim.x + threadIdx.x;
    if (i >= e) return;
    int d = dst[i];
    int pos = rs[d] + atomicAdd(&cur[d], 1);
    csr[pos] = src[i];
}

// ================= layer-0 GEMM (K = F_IN = 11) =================
__global__ __launch_bounds__(256) void k_gemm0(
    const float* __restrict__ x, const float* __restrict__ W,
    const float* __restrict__ dinv, float* __restrict__ hs, int n, int fin) {
    int row = blockIdx.x * 2 + (threadIdx.x >> 7);
    int f = threadIdx.x & 127;
    if (row >= n) return;
    float acc = 0.0f;
    for (int k = 0; k < fin; ++k)
        acc += x[row * fin + k] * W[k * HDIM + f];
    hs[row * HDIM + f] = acc * dinv[row];
}

// ================= main GEMM (128x128), 64-row tile =================
__global__ __launch_bounds__(256) void k_gemm(
    const float* __restrict__ x, const float* __restrict__ W,
    const float* __restrict__ dinv, float* __restrict__ hs, int n) {
    __shared__ float xs[64][HDIM];
    int row0 = blockIdx.x * 64;
    int tid = threadIdx.x;

    #pragma unroll
    for (int j = 0; j < 8; ++j) {
        int fid = tid + 256 * j;
        int r = fid >> 5, k4 = fid & 31;
        float4 v = make_float4(0.f, 0.f, 0.f, 0.f);
        int gr = row0 + r;
        if (gr < n) v = *(const float4*)(x + (size_t)gr * HDIM + k4 * 4);
        *(float4*)(&xs[r][k4 * 4]) = v;
    }
    __syncthreads();

    int rg = tid >> 5;
    int cg = tid & 31;
    float4 acc[8];
    #pragma unroll
    for (int r = 0; r < 8; ++r) acc[r] = make_float4(0.f, 0.f, 0.f, 0.f);

    for (int kk = 0; kk < HDIM; kk += 4) {
        float4 wv[4];
        #pragma unroll
        for (int k = 0; k < 4; ++k)
            wv[k] = *(const float4*)(W + (size_t)(kk + k) * HDIM + cg * 4);
        #pragma unroll
        for (int r = 0; r < 8; ++r) {
            float4 xv = *(const float4*)(&xs[rg * 8 + r][kk]);
            acc[r].x += xv.x * wv[0].x + xv.y * wv[1].x + xv.z * wv[2].x + xv.w * wv[3].x;
            acc[r].y += xv.x * wv[0].y + xv.y * wv[1].y + xv.z * wv[2].y + xv.w * wv[3].y;
            acc[r].z += xv.x * wv[0].z + xv.y * wv[1].z + xv.z * wv[2].z + xv.w * wv[3].z;
            acc[r].w += xv.x * wv[0].w + xv.y * wv[1].w + xv.z * wv[2].w + xv.w * wv[3].w;
        }
    }

    #pragma unroll
    for (int r = 0; r < 8; ++r) {
        int gr = row0 + rg * 8 + r;
        if (gr < n) {
            float s = dinv[gr];
            float4 o = make_float4(acc[r].x * s, acc[r].y * s, acc[r].z * s, acc[r].w * s);
            *(float4*)(hs + (size_t)gr * HDIM + cg * 4) = o;
        }
    }
}

// ========== fused CSR gather + bias + BN(eval) + ReLU + residual ==========
// 32 threads per node (float4 each); xnew may alias xold (same-thread RMW only)
__global__ __launch_bounds__(256) void k_agg(
    const int* __restrict__ rs, const int* __restrict__ deg,
    const int* __restrict__ csr, const float* __restrict__ hs,
    const float* __restrict__ dinv, const float* __restrict__ bias,
    const float* __restrict__ gamma, const float* __restrict__ beta,
    const float* __restrict__ mean, const float* __restrict__ var,
    const float* __restrict__ xold, float* __restrict__ xnew,
    int n, int use_res) {
    int node = blockIdx.x * 8 + (threadIdx.x >> 5);
    if (node >= n) return;
    int f4 = (threadIdx.x & 31) * 4;
    size_t base = (size_t)node * HDIM + f4;

    float4 acc = *(const float4*)(hs + base);            // self-loop term
    int start = rs[node];
    int d = deg[node];
    int j = 0;
    for (; j + 2 <= d; j += 2) {                         // unroll-2 for MLP
        int s0 = csr[start + j];
        int s1 = csr[start + j + 1];
        float4 v0 = *(const float4*)(hs + (size_t)s0 * HDIM + f4);
        float4 v1 = *(const float4*)(hs + (size_t)s1 * HDIM + f4);
        acc.x += v0.x + v1.x; acc.y += v0.y + v1.y;
        acc.z += v0.z + v1.z; acc.w += v0.w + v1.w;
    }
    if (j < d) {
        int s0 = csr[start + j];
        float4 v0 = *(const float4*)(hs + (size_t)s0 * HDIM + f4);
        acc.x += v0.x; acc.y += v0.y; acc.z += v0.z; acc.w += v0.w;
    }

    float di = dinv[node];
    float4 bv = *(const float4*)(bias + f4);
    float4 gv = *(const float4*)(gamma + f4);
    float4 be = *(const float4*)(beta + f4);
    float4 mv = *(const float4*)(mean + f4);
    float4 vv = *(const float4*)(var + f4);
    float4 o;
    o.x = fmaxf((di * acc.x + bv.x - mv.x) * rsqrtf(vv.x + BN_EPS) * gv.x + be.x, 0.f);
    o.y = fmaxf((di * acc.y + bv.y - mv.y) * rsqrtf(vv.y + BN_EPS) * gv.y + be.y, 0.f);
    o.z = fmaxf((di * acc.z + bv.z - mv.z) * rsqrtf(vv.z + BN_EPS) * gv.z + be.z, 0.f);
    o.w = fmaxf((di * acc.w + bv.w - mv.w) * rsqrtf(vv.w + BN_EPS) * gv.w + be.w, 0.f);
    if (use_res) {
        float4 xo = *(const float4*)(xold + base);
        o.x += xo.x; o.y += xo.y; o.z += xo.z; o.w += xo.w;
    }
    *(float4*)(xnew + base) = o;
}

// ================= pooling =================
__global__ void k_zero_pool(float* __restrict__ pooled, float* __restrict__ cnt, int g) {
    int t = blockIdx.x * blockDim.x + threadIdx.x;
    if (t < g * HDIM) pooled[t] = 0.f;
    if (t < g) cnt[t] = 0.f;
}

__global__ void k_pool(const float* __restrict__ x, const int* __restrict__ batch,
                       float* __restrict__ pooled, float* __restrict__ cnt, int n) {
    int t = blockIdx.x * blockDim.x + threadIdx.x;
    if (t >= n * 32) return;
    int row = t >> 5, f4 = (t & 31) * 4;
    int g = batch[row];
    float4 v = *(const float4*)(x + (size_t)row * HDIM + f4);
    float* p = pooled + (size_t)g * HDIM + f4;
    atomicAdd(p + 0, v.x);
    atomicAdd(p + 1, v.y);
    atomicAdd(p + 2, v.z);
    atomicAdd(p + 3, v.w);
    if ((t & 31) == 0) atomicAdd(&cnt[g], 1.0f);
}

// ================= head MLP =================
__global__ __launch_bounds__(64) void k_head(
    const float* __restrict__ pooled, const float* __restrict__ cnt,
    const float* __restrict__ w1, const float* __restrict__ b1,
    const float* __restrict__ w2, const float* __restrict__ b2,
    float* __restrict__ out) {
    __shared__ float p[HDIM];
    int g = blockIdx.x;
    int t = threadIdx.x;
    float inv = 1.0f / fmaxf(cnt[g], 1.0f);
    p[t]      = pooled[(size_t)g * HDIM + t] * inv;
    p[t + 64] = pooled[(size_t)g * HDIM + 64 + t] * inv;
    __syncthreads();
    float h = b1[t];
    #pragma unroll 4
    for (int k = 0; k < HDIM; ++k)
        h += p[k] * w1[k * 64 + t];
    h = fmaxf(h, 0.f);
    float part = h * w2[t];
    #pragma unroll
    for (int off = 32; off > 0; off >>= 1)
        part += __shfl_down(part, off);
    if (t == 0) out[g] = part + b2[0];
}

extern "C" void kernel_launch(void* const* d_in, const int* in_sizes, int n_in,
                              void* d_out, int out_size, void* d_ws, size_t ws_size,
                              hipStream_t stream) {
    const float* x0   = (const float*)d_in[0];
    const int*   eidx = (const int*)  d_in[1];
    const int*   batch= (const int*)  d_in[2];
    const float* W0   = (const float*)d_in[3];
    const float* b0   = (const float*)d_in[4];
    const float* Ws   = (const float*)d_in[5];
    const float* bs   = (const float*)d_in[6];
    const float* gam  = (const float*)d_in[7];
    const float* bet  = (const float*)d_in[8];
    const float* mean = (const float*)d_in[9];
    const float* var  = (const float*)d_in[10];
    const float* w1   = (const float*)d_in[11];
    const float* b1   = (const float*)d_in[12];
    const float* w2   = (const float*)d_in[13];
    const float* b2   = (const float*)d_in[14];

    const int FIN = 11;
    int n = in_sizes[0] / FIN;      // 50000
    int e = in_sizes[1] / 2;        // 600000
    int g = out_size;               // 2048
    int nb = (n + 255) / 256;       // scan blocks (196)

    const int* src = eidx;
    const int* dst = eidx + e;

    // ---- workspace carve-up ----
    char* ws = (char*)d_ws;
    size_t nal = ((size_t)n + 255) & ~(size_t)255;
    int*   deg   = (int*)ws;                       ws += nal * 4;
    int*   cur   = (int*)ws;                       ws += nal * 4;
    int*   rs    = (int*)ws;                       ws += nal * 4;
    int*   blk   = (int*)ws;                       ws += 256 * 4;
    int*   csr   = (int*)ws;                       ws += ((size_t)e + 63) / 64 * 64 * 4;
    float* dinv  = (float*)ws;                     ws += nal * 4;
    float* bufA  = (float*)ws;                     ws += (size_t)n * HDIM * 4;
    float* bufB  = (float*)ws;                     ws += (size_t)n * HDIM * 4;
    float* pooled= (float*)ws;                     ws += (size_t)g * HDIM * 4;
    float* cnt   = (float*)ws;

    // ---- prologue: degree, dinv, CSR ----
    k_zero2<<<nb, 256, 0, stream>>>(deg, cur, n);
    k_deg_accum<<<(e + 255) / 256, 256, 0, stream>>>(dst, deg, e);
    k_dinv<<<nb, 256, 0, stream>>>(deg, dinv, n);
    k_scan1<<<nb, 256, 0, stream>>>(deg, rs, blk, n);
    k_scan2<<<1, 256, 0, stream>>>(blk, nb);
    k_scan3<<<nb, 256, 0, stream>>>(rs, blk, n);
    k_fill<<<(e + 255) / 256, 256, 0, stream>>>(src, dst, rs, cur, csr, e);

    // ---- 5 GCN layers: x lives in bufA, hs in bufB ----
    for (int i = 0; i < 5; ++i) {
        const float* xin = (i == 0) ? x0 : bufA;
        const float* bias = (i == 0) ? b0 : bs + (size_t)(i - 1) * HDIM;
        if (i == 0) {
            k_gemm0<<<(n + 1) / 2, 256, 0, stream>>>(x0, W0, dinv, bufB, n, FIN);
        } else {
            const float* W = Ws + (size_t)(i - 1) * HDIM * HDIM;
            k_gemm<<<(n + 63) / 64, 256, 0, stream>>>(bufA, W, dinv, bufB, n);
        }
        k_agg<<<(n + 7) / 8, 256, 0, stream>>>(
            rs, deg, csr, bufB, dinv, bias,
            gam + i * HDIM, bet + i * HDIM, mean + i * HDIM, var + i * HDIM,
            xin, bufA, n, (i > 0) ? 1 : 0);
    }

    // ---- global mean pool + head ----
    k_zero_pool<<<((size_t)g * HDIM + 255) / 256, 256, 0, stream>>>(pooled, cnt, g);
    k_pool<<<((size_t)n * 32 + 255) / 256, 256, 0, stream>>>(bufA, batch, pooled, cnt, n);
    k_head<<<g, 64, 0, stream>>>(pooled, cnt, w1, b1, w2, b2, (float*)d_out);
}

// Round 4
// 588.530 us; speedup vs baseline: 9.3814x; 1.1970x over previous
//
#include <hip/hip_runtime.h>

#define HDIM 128
#define BN_EPS 1e-5f

// ================= prologue: degree, dinv, CSR build =================

__global__ void k_zero2(int* __restrict__ a, int* __restrict__ b, int n) {
    int i = blockIdx.x * blockDim.x + threadIdx.x;
    if (i < n) { a[i] = 0; b[i] = 0; }
}

__global__ void k_deg_accum(const int* __restrict__ dst, int* __restrict__ deg, int e) {
    int i = blockIdx.x * blockDim.x + threadIdx.x;
    if (i < e) atomicAdd(&deg[dst[i]], 1);
}

__global__ void k_dinv(const int* __restrict__ deg, float* __restrict__ dinv, int n) {
    int i = blockIdx.x * blockDim.x + threadIdx.x;
    if (i < n) dinv[i] = rsqrtf((float)deg[i] + 1.0f);   // +1 self-loop
}

// exclusive scan of deg -> rs, 3-kernel hierarchical
__global__ void k_scan1(const int* __restrict__ deg, int* __restrict__ rs,
                        int* __restrict__ blk, int n) {
    __shared__ int s[256];
    int i = blockIdx.x * 256 + threadIdx.x;
    int v = (i < n) ? deg[i] : 0;
    s[threadIdx.x] = v;
    __syncthreads();
    for (int off = 1; off < 256; off <<= 1) {
        int t = (threadIdx.x >= off) ? s[threadIdx.x - off] : 0;
        __syncthreads();
        s[threadIdx.x] += t;
        __syncthreads();
    }
    if (i < n) rs[i] = s[threadIdx.x] - v;               // exclusive
    if (threadIdx.x == 255) blk[blockIdx.x] = s[255];
}

__global__ void k_scan2(int* __restrict__ blk, int nb) {
    __shared__ int s[256];
    int t = threadIdx.x;
    int v = (t < nb) ? blk[t] : 0;
    s[t] = v;
    __syncthreads();
    for (int off = 1; off < 256; off <<= 1) {
        int u = (t >= off) ? s[t - off] : 0;
        __syncthreads();
        s[t] += u;
        __syncthreads();
    }
    if (t < nb) blk[t] = s[t] - v;                       // exclusive
}

__global__ void k_scan3(int* __restrict__ rs, const int* __restrict__ blk, int n) {
    int i = blockIdx.x * 256 + threadIdx.x;
    if (i < n) rs[i] += blk[blockIdx.x];
}

__global__ void k_fill(const int* __restrict__ src, const int* __restrict__ dst,
                       const int* __restrict__ rs, int* __restrict__ cur,
                       int* __restrict__ csr, int e) {
    int i = blockIdx.x * blockDim.x + threadIdx.x;
    if (i >= e) return;
    int d = dst[i];
    int pos = rs[d] + atomicAdd(&cur[d], 1);
    csr[pos] = src[i];
}

// graph boundaries from sorted batch: bnd[g] = first node with batch >= g
__global__ void k_bounds(const int* __restrict__ batch, int* __restrict__ bnd,
                         int n, int g) {
    int i = blockIdx.x * blockDim.x + threadIdx.x;
    if (i >= n) return;
    int b = batch[i];
    if (i == 0) {
        for (int q = 0; q <= b; ++q) bnd[q] = 0;
    } else {
        int p = batch[i - 1];
        for (int q = p + 1; q <= b; ++q) bnd[q] = i;
    }
    if (i == n - 1) {
        for (int q = b + 1; q <= g; ++q) bnd[q] = n;
    }
}

// ================= layer-0 GEMM (K = F_IN = 11) =================
__global__ __launch_bounds__(256) void k_gemm0(
    const float* __restrict__ x, const float* __restrict__ W,
    const float* __restrict__ dinv, float* __restrict__ hs, int n, int fin) {
    int row = blockIdx.x * 2 + (threadIdx.x >> 7);
    int f = threadIdx.x & 127;
    if (row >= n) return;
    float acc = 0.0f;
    for (int k = 0; k < fin; ++k)
        acc += x[row * fin + k] * W[k * HDIM + f];
    hs[row * HDIM + f] = acc * dinv[row];
}

// ================= main GEMM (128x128), 64-row tile =================
__global__ __launch_bounds__(256) void k_gemm(
    const float* __restrict__ x, const float* __restrict__ W,
    const float* __restrict__ dinv, float* __restrict__ hs, int n) {
    __shared__ float xs[64][HDIM];
    int row0 = blockIdx.x * 64;
    int tid = threadIdx.x;

    #pragma unroll
    for (int j = 0; j < 8; ++j) {
        int fid = tid + 256 * j;
        int r = fid >> 5, k4 = fid & 31;
        float4 v = make_float4(0.f, 0.f, 0.f, 0.f);
        int gr = row0 + r;
        if (gr < n) v = *(const float4*)(x + (size_t)gr * HDIM + k4 * 4);
        *(float4*)(&xs[r][k4 * 4]) = v;
    }
    __syncthreads();

    int rg = tid >> 5;
    int cg = tid & 31;
    float4 acc[8];
    #pragma unroll
    for (int r = 0; r < 8; ++r) acc[r] = make_float4(0.f, 0.f, 0.f, 0.f);

    for (int kk = 0; kk < HDIM; kk += 4) {
        float4 wv[4];
        #pragma unroll
        for (int k = 0; k < 4; ++k)
            wv[k] = *(const float4*)(W + (size_t)(kk + k) * HDIM + cg * 4);
        #pragma unroll
        for (int r = 0; r < 8; ++r) {
            float4 xv = *(const float4*)(&xs[rg * 8 + r][kk]);
            acc[r].x += xv.x * wv[0].x + xv.y * wv[1].x + xv.z * wv[2].x + xv.w * wv[3].x;
            acc[r].y += xv.x * wv[0].y + xv.y * wv[1].y + xv.z * wv[2].y + xv.w * wv[3].y;
            acc[r].z += xv.x * wv[0].z + xv.y * wv[1].z + xv.z * wv[2].z + xv.w * wv[3].z;
            acc[r].w += xv.x * wv[0].w + xv.y * wv[1].w + xv.z * wv[2].w + xv.w * wv[3].w;
        }
    }

    #pragma unroll
    for (int r = 0; r < 8; ++r) {
        int gr = row0 + rg * 8 + r;
        if (gr < n) {
            float s = dinv[gr];
            float4 o = make_float4(acc[r].x * s, acc[r].y * s, acc[r].z * s, acc[r].w * s);
            *(float4*)(hs + (size_t)gr * HDIM + cg * 4) = o;
        }
    }
}

// ========== fused CSR gather + bias + BN(eval) + ReLU + residual ==========
// 32 threads per node (float4 each); unroll-4 for memory-level parallelism
__global__ __launch_bounds__(256) void k_agg(
    const int* __restrict__ rs, const int* __restrict__ deg,
    const int* __restrict__ csr, const float* __restrict__ hs,
    const float* __restrict__ dinv, const float* __restrict__ bias,
    const float* __restrict__ gamma, const float* __restrict__ beta,
    const float* __restrict__ mean, const float* __restrict__ var,
    const float* __restrict__ xold, float* __restrict__ xnew,
    int n, int use_res) {
    int node = blockIdx.x * 8 + (threadIdx.x >> 5);
    if (node >= n) return;
    int f4 = (threadIdx.x & 31) * 4;
    size_t base = (size_t)node * HDIM + f4;

    float4 a0 = *(const float4*)(hs + base);             // self-loop term
    float4 a1 = make_float4(0.f, 0.f, 0.f, 0.f);
    float4 a2 = make_float4(0.f, 0.f, 0.f, 0.f);
    float4 a3 = make_float4(0.f, 0.f, 0.f, 0.f);
    int start = rs[node];
    int d = deg[node];
    int j = 0;
    for (; j + 4 <= d; j += 4) {
        int s0 = csr[start + j];
        int s1 = csr[start + j + 1];
        int s2 = csr[start + j + 2];
        int s3 = csr[start + j + 3];
        float4 v0 = *(const float4*)(hs + (size_t)s0 * HDIM + f4);
        float4 v1 = *(const float4*)(hs + (size_t)s1 * HDIM + f4);
        float4 v2 = *(const float4*)(hs + (size_t)s2 * HDIM + f4);
        float4 v3 = *(const float4*)(hs + (size_t)s3 * HDIM + f4);
        a0.x += v0.x; a0.y += v0.y; a0.z += v0.z; a0.w += v0.w;
        a1.x += v1.x; a1.y += v1.y; a1.z += v1.z; a1.w += v1.w;
        a2.x += v2.x; a2.y += v2.y; a2.z += v2.z; a2.w += v2.w;
        a3.x += v3.x; a3.y += v3.y; a3.z += v3.z; a3.w += v3.w;
    }
    for (; j < d; ++j) {
        int s0 = csr[start + j];
        float4 v0 = *(const float4*)(hs + (size_t)s0 * HDIM + f4);
        a0.x += v0.x; a0.y += v0.y; a0.z += v0.z; a0.w += v0.w;
    }
    float4 acc;
    acc.x = (a0.x + a1.x) + (a2.x + a3.x);
    acc.y = (a0.y + a1.y) + (a2.y + a3.y);
    acc.z = (a0.z + a1.z) + (a2.z + a3.z);
    acc.w = (a0.w + a1.w) + (a2.w + a3.w);

    float di = dinv[node];
    float4 bv = *(const float4*)(bias + f4);
    float4 gv = *(const float4*)(gamma + f4);
    float4 be = *(const float4*)(beta + f4);
    float4 mv = *(const float4*)(mean + f4);
    float4 vv = *(const float4*)(var + f4);
    float4 o;
    o.x = fmaxf((di * acc.x + bv.x - mv.x) * rsqrtf(vv.x + BN_EPS) * gv.x + be.x, 0.f);
    o.y = fmaxf((di * acc.y + bv.y - mv.y) * rsqrtf(vv.y + BN_EPS) * gv.y + be.y, 0.f);
    o.z = fmaxf((di * acc.z + bv.z - mv.z) * rsqrtf(vv.z + BN_EPS) * gv.z + be.z, 0.f);
    o.w = fmaxf((di * acc.w + bv.w - mv.w) * rsqrtf(vv.w + BN_EPS) * gv.w + be.w, 0.f);
    if (use_res) {
        float4 xo = *(const float4*)(xold + base);
        o.x += xo.x; o.y += xo.y; o.z += xo.z; o.w += xo.w;
    }
    *(float4*)(xnew + base) = o;
}

// ================= segmented mean-pool (no atomics; batch sorted) =================
// one 32-lane group per graph; writes the already-averaged mean
__global__ __launch_bounds__(256) void k_pool_seg(
    const float* __restrict__ x, const int* __restrict__ bnd,
    float* __restrict__ pooled, int g) {
    int gid = blockIdx.x * 8 + (threadIdx.x >> 5);
    if (gid >= g) return;
    int f4 = (threadIdx.x & 31) * 4;
    int s = bnd[gid], t = bnd[gid + 1];
    float4 a0 = make_float4(0.f, 0.f, 0.f, 0.f);
    float4 a1 = make_float4(0.f, 0.f, 0.f, 0.f);
    int r = s;
    for (; r + 2 <= t; r += 2) {
        float4 v0 = *(const float4*)(x + (size_t)r * HDIM + f4);
        float4 v1 = *(const float4*)(x + (size_t)(r + 1) * HDIM + f4);
        a0.x += v0.x; a0.y += v0.y; a0.z += v0.z; a0.w += v0.w;
        a1.x += v1.x; a1.y += v1.y; a1.z += v1.z; a1.w += v1.w;
    }
    if (r < t) {
        float4 v0 = *(const float4*)(x + (size_t)r * HDIM + f4);
        a0.x += v0.x; a0.y += v0.y; a0.z += v0.z; a0.w += v0.w;
    }
    float inv = (t > s) ? 1.0f / (float)(t - s) : 0.0f;
    float4 o = make_float4((a0.x + a1.x) * inv, (a0.y + a1.y) * inv,
                           (a0.z + a1.z) * inv, (a0.w + a1.w) * inv);
    *(float4*)(pooled + (size_t)gid * HDIM + f4) = o;
}

// ================= head MLP (pooled already averaged) =================
__global__ __launch_bounds__(64) void k_head(
    const float* __restrict__ pooled,
    const float* __restrict__ w1, const float* __restrict__ b1,
    const float* __restrict__ w2, const float* __restrict__ b2,
    float* __restrict__ out) {
    __shared__ float p[HDIM];
    int g = blockIdx.x;
    int t = threadIdx.x;
    p[t]      = pooled[(size_t)g * HDIM + t];
    p[t + 64] = pooled[(size_t)g * HDIM + 64 + t];
    __syncthreads();
    float h = b1[t];
    #pragma unroll 4
    for (int k = 0; k < HDIM; ++k)
        h += p[k] * w1[k * 64 + t];
    h = fmaxf(h, 0.f);
    float part = h * w2[t];
    #pragma unroll
    for (int off = 32; off > 0; off >>= 1)
        part += __shfl_down(part, off);
    if (t == 0) out[g] = part + b2[0];
}

extern "C" void kernel_launch(void* const* d_in, const int* in_sizes, int n_in,
                              void* d_out, int out_size, void* d_ws, size_t ws_size,
                              hipStream_t stream) {
    const float* x0   = (const float*)d_in[0];
    const int*   eidx = (const int*)  d_in[1];
    const int*   batch= (const int*)  d_in[2];
    const float* W0   = (const float*)d_in[3];
    const float* b0   = (const float*)d_in[4];
    const float* Ws   = (const float*)d_in[5];
    const float* bs   = (const float*)d_in[6];
    const float* gam  = (const float*)d_in[7];
    const float* bet  = (const float*)d_in[8];
    const float* mean = (const float*)d_in[9];
    const float* var  = (const float*)d_in[10];
    const float* w1   = (const float*)d_in[11];
    const float* b1   = (const float*)d_in[12];
    const float* w2   = (const float*)d_in[13];
    const float* b2   = (const float*)d_in[14];

    const int FIN = 11;
    int n = in_sizes[0] / FIN;      // 50000
    int e = in_sizes[1] / 2;        // 600000
    int g = out_size;               // 2048
    int nb = (n + 255) / 256;       // scan blocks

    const int* src = eidx;
    const int* dst = eidx + e;

    // ---- workspace carve-up ----
    char* ws = (char*)d_ws;
    size_t nal = ((size_t)n + 255) & ~(size_t)255;
    int*   deg   = (int*)ws;                       ws += nal * 4;
    int*   cur   = (int*)ws;                       ws += nal * 4;
    int*   rs    = (int*)ws;                       ws += nal * 4;
    int*   blk   = (int*)ws;                       ws += 256 * 4;
    int*   bnd   = (int*)ws;                       ws += ((size_t)g + 64) / 64 * 64 * 4;
    int*   csr   = (int*)ws;                       ws += ((size_t)e + 63) / 64 * 64 * 4;
    float* dinv  = (float*)ws;                     ws += nal * 4;
    float* bufA  = (float*)ws;                     ws += (size_t)n * HDIM * 4;
    float* bufB  = (float*)ws;                     ws += (size_t)n * HDIM * 4;
    float* pooled= (float*)ws;

    // ---- prologue: degree, dinv, CSR, graph bounds ----
    k_zero2<<<nb, 256, 0, stream>>>(deg, cur, n);
    k_deg_accum<<<(e + 255) / 256, 256, 0, stream>>>(dst, deg, e);
    k_dinv<<<nb, 256, 0, stream>>>(deg, dinv, n);
    k_scan1<<<nb, 256, 0, stream>>>(deg, rs, blk, n);
    k_scan2<<<1, 256, 0, stream>>>(blk, nb);
    k_scan3<<<nb, 256, 0, stream>>>(rs, blk, n);
    k_fill<<<(e + 255) / 256, 256, 0, stream>>>(src, dst, rs, cur, csr, e);
    k_bounds<<<nb, 256, 0, stream>>>(batch, bnd, n, g);

    // ---- 5 GCN layers: x lives in bufA, hs in bufB ----
    for (int i = 0; i < 5; ++i) {
        const float* xin = (i == 0) ? x0 : bufA;
        const float* bias = (i == 0) ? b0 : bs + (size_t)(i - 1) * HDIM;
        if (i == 0) {
            k_gemm0<<<(n + 1) / 2, 256, 0, stream>>>(x0, W0, dinv, bufB, n, FIN);
        } else {
            const float* W = Ws + (size_t)(i - 1) * HDIM * HDIM;
            k_gemm<<<(n + 63) / 64, 256, 0, stream>>>(bufA, W, dinv, bufB, n);
        }
        k_agg<<<(n + 7) / 8, 256, 0, stream>>>(
            rs, deg, csr, bufB, dinv, bias,
            gam + i * HDIM, bet + i * HDIM, mean + i * HDIM, var + i * HDIM,
            xin, bufA, n, (i > 0) ? 1 : 0);
    }

    // ---- segmented mean pool + head ----
    k_pool_seg<<<(g + 7) / 8, 256, 0, stream>>>(bufA, bnd, pooled, g);
    k_head<<<g, 64, 0, stream>>>(pooled, w1, b1, w2, b2, (float*)d_out);
}

// Round 5
// 516.379 us; speedup vs baseline: 10.6922x; 1.1397x over previous
//
#include <hip/hip_runtime.h>
#include <hip/hip_fp16.h>

#define HDIM 128
#define BN_EPS 1e-5f

// ---- fp16 helpers: hs (message payload) is stored as __half ----
__device__ inline float4 ld_h4(const __half* p) {
    uint2 raw = *(const uint2*)p;
    __half2 h01 = *(__half2*)&raw.x;
    __half2 h23 = *(__half2*)&raw.y;
    float2 f01 = __half22float2(h01);
    float2 f23 = __half22float2(h23);
    return make_float4(f01.x, f01.y, f23.x, f23.y);
}

__device__ inline void st_h4(__half* p, float4 v) {
    __half2 p01 = __floats2half2_rn(v.x, v.y);
    __half2 p23 = __floats2half2_rn(v.z, v.w);
    uint2 bits;
    bits.x = *(unsigned int*)&p01;
    bits.y = *(unsigned int*)&p23;
    *(uint2*)p = bits;
}

// ================= prologue: degree, dinv, CSR build =================

__global__ void k_zero2(int* __restrict__ a, int* __restrict__ b, int n) {
    int i = blockIdx.x * blockDim.x + threadIdx.x;
    if (i < n) { a[i] = 0; b[i] = 0; }
}

__global__ void k_deg_accum(const int* __restrict__ dst, int* __restrict__ deg, int e) {
    int i = blockIdx.x * blockDim.x + threadIdx.x;
    if (i < e) atomicAdd(&deg[dst[i]], 1);
}

__global__ void k_dinv(const int* __restrict__ deg, float* __restrict__ dinv, int n) {
    int i = blockIdx.x * blockDim.x + threadIdx.x;
    if (i < n) dinv[i] = rsqrtf((float)deg[i] + 1.0f);   // +1 self-loop
}

// exclusive scan of deg -> rs, 3-kernel hierarchical
__global__ void k_scan1(const int* __restrict__ deg, int* __restrict__ rs,
                        int* __restrict__ blk, int n) {
    __shared__ int s[256];
    int i = blockIdx.x * 256 + threadIdx.x;
    int v = (i < n) ? deg[i] : 0;
    s[threadIdx.x] = v;
    __syncthreads();
    for (int off = 1; off < 256; off <<= 1) {
        int t = (threadIdx.x >= off) ? s[threadIdx.x - off] : 0;
        __syncthreads();
        s[threadIdx.x] += t;
        __syncthreads();
    }
    if (i < n) rs[i] = s[threadIdx.x] - v;               // exclusive
    if (threadIdx.x == 255) blk[blockIdx.x] = s[255];
}

__global__ void k_scan2(int* __restrict__ blk, int nb) {
    __shared__ int s[256];
    int t = threadIdx.x;
    int v = (t < nb) ? blk[t] : 0;
    s[t] = v;
    __syncthreads();
    for (int off = 1; off < 256; off <<= 1) {
        int u = (t >= off) ? s[t - off] : 0;
        __syncthreads();
        s[t] += u;
        __syncthreads();
    }
    if (t < nb) blk[t] = s[t] - v;                       // exclusive
}

__global__ void k_scan3(int* __restrict__ rs, const int* __restrict__ blk, int n) {
    int i = blockIdx.x * 256 + threadIdx.x;
    if (i < n) rs[i] += blk[blockIdx.x];
}

__global__ void k_fill(const int* __restrict__ src, const int* __restrict__ dst,
                       const int* __restrict__ rs, int* __restrict__ cur,
                       int* __restrict__ csr, int e) {
    int i = blockIdx.x * blockDim.x + threadIdx.x;
    if (i >= e) return;
    int d = dst[i];
    int pos = rs[d] + atomicAdd(&cur[d], 1);
    csr[pos] = src[i];
}

// graph boundaries from sorted batch: bnd[g] = first node with batch >= g
__global__ void k_bounds(const int* __restrict__ batch, int* __restrict__ bnd,
                         int n, int g) {
    int i = blockIdx.x * blockDim.x + threadIdx.x;
    if (i >= n) return;
    int b = batch[i];
    if (i == 0) {
        for (int q = 0; q <= b; ++q) bnd[q] = 0;
    } else {
        int p = batch[i - 1];
        for (int q = p + 1; q <= b; ++q) bnd[q] = i;
    }
    if (i == n - 1) {
        for (int q = b + 1; q <= g; ++q) bnd[q] = n;
    }
}

// ================= layer-0 GEMM (K = F_IN = 11) =================
__global__ __launch_bounds__(256) void k_gemm0(
    const float* __restrict__ x, const float* __restrict__ W,
    const float* __restrict__ dinv, __half* __restrict__ hs, int n, int fin) {
    int row = blockIdx.x * 2 + (threadIdx.x >> 7);
    int f = threadIdx.x & 127;
    if (row >= n) return;
    float acc = 0.0f;
    for (int k = 0; k < fin; ++k)
        acc += x[row * fin + k] * W[k * HDIM + f];
    hs[(size_t)row * HDIM + f] = __float2half_rn(acc * dinv[row]);
}

// ================= main GEMM (128x128), 64-row tile, W reg-dbuf =================
__global__ __launch_bounds__(256) void k_gemm(
    const float* __restrict__ x, const float* __restrict__ W,
    const float* __restrict__ dinv, __half* __restrict__ hs, int n) {
    __shared__ float xs[64][HDIM];
    int row0 = blockIdx.x * 64;
    int tid = threadIdx.x;

    #pragma unroll
    for (int j = 0; j < 8; ++j) {
        int fid = tid + 256 * j;
        int r = fid >> 5, k4 = fid & 31;
        float4 v = make_float4(0.f, 0.f, 0.f, 0.f);
        int gr = row0 + r;
        if (gr < n) v = *(const float4*)(x + (size_t)gr * HDIM + k4 * 4);
        *(float4*)(&xs[r][k4 * 4]) = v;
    }
    __syncthreads();

    int rg = tid >> 5;
    int cg = tid & 31;
    float4 acc[8];
    #pragma unroll
    for (int r = 0; r < 8; ++r) acc[r] = make_float4(0.f, 0.f, 0.f, 0.f);

    // register double-buffer for W rows: prefetch kk+4 while computing kk
    float4 wv[4], wn[4];
    #pragma unroll
    for (int k = 0; k < 4; ++k)
        wv[k] = *(const float4*)(W + (size_t)k * HDIM + cg * 4);

    for (int kk = 0; kk < HDIM; kk += 4) {
        if (kk + 4 < HDIM) {
            #pragma unroll
            for (int k = 0; k < 4; ++k)
                wn[k] = *(const float4*)(W + (size_t)(kk + 4 + k) * HDIM + cg * 4);
        }
        #pragma unroll
        for (int r = 0; r < 8; ++r) {
            float4 xv = *(const float4*)(&xs[rg * 8 + r][kk]);
            acc[r].x += xv.x * wv[0].x + xv.y * wv[1].x + xv.z * wv[2].x + xv.w * wv[3].x;
            acc[r].y += xv.x * wv[0].y + xv.y * wv[1].y + xv.z * wv[2].y + xv.w * wv[3].y;
            acc[r].z += xv.x * wv[0].z + xv.y * wv[1].z + xv.z * wv[2].z + xv.w * wv[3].z;
            acc[r].w += xv.x * wv[0].w + xv.y * wv[1].w + xv.z * wv[2].w + xv.w * wv[3].w;
        }
        #pragma unroll
        for (int k = 0; k < 4; ++k) wv[k] = wn[k];
    }

    #pragma unroll
    for (int r = 0; r < 8; ++r) {
        int gr = row0 + rg * 8 + r;
        if (gr < n) {
            float s = dinv[gr];
            float4 o = make_float4(acc[r].x * s, acc[r].y * s, acc[r].z * s, acc[r].w * s);
            st_h4(hs + (size_t)gr * HDIM + cg * 4, o);
        }
    }
}

// ========== fused CSR gather (fp16 payload) + bias + BN + ReLU + residual ==========
// 32 threads per node (4 halfs = 8 B each); unroll-4 for MLP; accum fp32
__global__ __launch_bounds__(256) void k_agg(
    const int* __restrict__ rs, const int* __restrict__ deg,
    const int* __restrict__ csr, const __half* __restrict__ hs,
    const float* __restrict__ dinv, const float* __restrict__ bias,
    const float* __restrict__ gamma, const float* __restrict__ beta,
    const float* __restrict__ mean, const float* __restrict__ var,
    const float* __restrict__ xold, float* __restrict__ xnew,
    int n, int use_res) {
    int node = blockIdx.x * 8 + (threadIdx.x >> 5);
    if (node >= n) return;
    int f4 = (threadIdx.x & 31) * 4;
    size_t base = (size_t)node * HDIM + f4;

    float4 a0 = ld_h4(hs + base);                        // self-loop term
    float4 a1 = make_float4(0.f, 0.f, 0.f, 0.f);
    float4 a2 = make_float4(0.f, 0.f, 0.f, 0.f);
    float4 a3 = make_float4(0.f, 0.f, 0.f, 0.f);
    int start = rs[node];
    int d = deg[node];
    int j = 0;
    for (; j + 4 <= d; j += 4) {
        int s0 = csr[start + j];
        int s1 = csr[start + j + 1];
        int s2 = csr[start + j + 2];
        int s3 = csr[start + j + 3];
        float4 v0 = ld_h4(hs + (size_t)s0 * HDIM + f4);
        float4 v1 = ld_h4(hs + (size_t)s1 * HDIM + f4);
        float4 v2 = ld_h4(hs + (size_t)s2 * HDIM + f4);
        float4 v3 = ld_h4(hs + (size_t)s3 * HDIM + f4);
        a0.x += v0.x; a0.y += v0.y; a0.z += v0.z; a0.w += v0.w;
        a1.x += v1.x; a1.y += v1.y; a1.z += v1.z; a1.w += v1.w;
        a2.x += v2.x; a2.y += v2.y; a2.z += v2.z; a2.w += v2.w;
        a3.x += v3.x; a3.y += v3.y; a3.z += v3.z; a3.w += v3.w;
    }
    for (; j < d; ++j) {
        int s0 = csr[start + j];
        float4 v0 = ld_h4(hs + (size_t)s0 * HDIM + f4);
        a0.x += v0.x; a0.y += v0.y; a0.z += v0.z; a0.w += v0.w;
    }
    float4 acc;
    acc.x = (a0.x + a1.x) + (a2.x + a3.x);
    acc.y = (a0.y + a1.y) + (a2.y + a3.y);
    acc.z = (a0.z + a1.z) + (a2.z + a3.z);
    acc.w = (a0.w + a1.w) + (a2.w + a3.w);

    float di = dinv[node];
    float4 bv = *(const float4*)(bias + f4);
    float4 gv = *(const float4*)(gamma + f4);
    float4 be = *(const float4*)(beta + f4);
    float4 mv = *(const float4*)(mean + f4);
    float4 vv = *(const float4*)(var + f4);
    float4 o;
    o.x = fmaxf((di * acc.x + bv.x - mv.x) * rsqrtf(vv.x + BN_EPS) * gv.x + be.x, 0.f);
    o.y = fmaxf((di * acc.y + bv.y - mv.y) * rsqrtf(vv.y + BN_EPS) * gv.y + be.y, 0.f);
    o.z = fmaxf((di * acc.z + bv.z - mv.z) * rsqrtf(vv.z + BN_EPS) * gv.z + be.z, 0.f);
    o.w = fmaxf((di * acc.w + bv.w - mv.w) * rsqrtf(vv.w + BN_EPS) * gv.w + be.w, 0.f);
    if (use_res) {
        float4 xo = *(const float4*)(xold + base);
        o.x += xo.x; o.y += xo.y; o.z += xo.z; o.w += xo.w;
    }
    *(float4*)(xnew + base) = o;
}

// ================= segmented mean-pool (no atomics; batch sorted) =================
__global__ __launch_bounds__(256) void k_pool_seg(
    const float* __restrict__ x, const int* __restrict__ bnd,
    float* __restrict__ pooled, int g) {
    int gid = blockIdx.x * 8 + (threadIdx.x >> 5);
    if (gid >= g) return;
    int f4 = (threadIdx.x & 31) * 4;
    int s = bnd[gid], t = bnd[gid + 1];
    float4 a0 = make_float4(0.f, 0.f, 0.f, 0.f);
    float4 a1 = make_float4(0.f, 0.f, 0.f, 0.f);
    int r = s;
    for (; r + 2 <= t; r += 2) {
        float4 v0 = *(const float4*)(x + (size_t)r * HDIM + f4);
        float4 v1 = *(const float4*)(x + (size_t)(r + 1) * HDIM + f4);
        a0.x += v0.x; a0.y += v0.y; a0.z += v0.z; a0.w += v0.w;
        a1.x += v1.x; a1.y += v1.y; a1.z += v1.z; a1.w += v1.w;
    }
    if (r < t) {
        float4 v0 = *(const float4*)(x + (size_t)r * HDIM + f4);
        a0.x += v0.x; a0.y += v0.y; a0.z += v0.z; a0.w += v0.w;
    }
    float inv = (t > s) ? 1.0f / (float)(t - s) : 0.0f;
    float4 o = make_float4((a0.x + a1.x) * inv, (a0.y + a1.y) * inv,
                           (a0.z + a1.z) * inv, (a0.w + a1.w) * inv);
    *(float4*)(pooled + (size_t)gid * HDIM + f4) = o;
}

// ================= head MLP (pooled already averaged) =================
__global__ __launch_bounds__(64) void k_head(
    const float* __restrict__ pooled,
    const float* __restrict__ w1, const float* __restrict__ b1,
    const float* __restrict__ w2, const float* __restrict__ b2,
    float* __restrict__ out) {
    __shared__ float p[HDIM];
    int g = blockIdx.x;
    int t = threadIdx.x;
    p[t]      = pooled[(size_t)g * HDIM + t];
    p[t + 64] = pooled[(size_t)g * HDIM + 64 + t];
    __syncthreads();
    float h = b1[t];
    #pragma unroll 4
    for (int k = 0; k < HDIM; ++k)
        h += p[k] * w1[k * 64 + t];
    h = fmaxf(h, 0.f);
    float part = h * w2[t];
    #pragma unroll
    for (int off = 32; off > 0; off >>= 1)
        part += __shfl_down(part, off);
    if (t == 0) out[g] = part + b2[0];
}

extern "C" void kernel_launch(void* const* d_in, const int* in_sizes, int n_in,
                              void* d_out, int out_size, void* d_ws, size_t ws_size,
                              hipStream_t stream) {
    const float* x0   = (const float*)d_in[0];
    const int*   eidx = (const int*)  d_in[1];
    const int*   batch= (const int*)  d_in[2];
    const float* W0   = (const float*)d_in[3];
    const float* b0   = (const float*)d_in[4];
    const float* Ws   = (const float*)d_in[5];
    const float* bs   = (const float*)d_in[6];
    const float* gam  = (const float*)d_in[7];
    const float* bet  = (const float*)d_in[8];
    const float* mean = (const float*)d_in[9];
    const float* var  = (const float*)d_in[10];
    const float* w1   = (const float*)d_in[11];
    const float* b1   = (const float*)d_in[12];
    const float* w2   = (const float*)d_in[13];
    const float* b2   = (const float*)d_in[14];

    const int FIN = 11;
    int n = in_sizes[0] / FIN;      // 50000
    int e = in_sizes[1] / 2;        // 600000
    int g = out_size;               // 2048
    int nb = (n + 255) / 256;       // scan blocks

    const int* src = eidx;
    const int* dst = eidx + e;

    // ---- workspace carve-up ----
    char* ws = (char*)d_ws;
    size_t nal = ((size_t)n + 255) & ~(size_t)255;
    int*    deg   = (int*)ws;                      ws += nal * 4;
    int*    cur   = (int*)ws;                      ws += nal * 4;
    int*    rs    = (int*)ws;                      ws += nal * 4;
    int*    blk   = (int*)ws;                      ws += 256 * 4;
    int*    bnd   = (int*)ws;                      ws += ((size_t)g + 64) / 64 * 64 * 4;
    int*    csr   = (int*)ws;                      ws += ((size_t)e + 63) / 64 * 64 * 4;
    float*  dinv  = (float*)ws;                    ws += nal * 4;
    float*  bufA  = (float*)ws;                    ws += (size_t)n * HDIM * 4;   // x (fp32)
    __half* bufH  = (__half*)ws;                   ws += (size_t)n * HDIM * 2;   // hs (fp16)
    float*  pooled= (float*)ws;

    // ---- prologue: degree, dinv, CSR, graph bounds ----
    k_zero2<<<nb, 256, 0, stream>>>(deg, cur, n);
    k_deg_accum<<<(e + 255) / 256, 256, 0, stream>>>(dst, deg, e);
    k_dinv<<<nb, 256, 0, stream>>>(deg, dinv, n);
    k_scan1<<<nb, 256, 0, stream>>>(deg, rs, blk, n);
    k_scan2<<<1, 256, 0, stream>>>(blk, nb);
    k_scan3<<<nb, 256, 0, stream>>>(rs, blk, n);
    k_fill<<<(e + 255) / 256, 256, 0, stream>>>(src, dst, rs, cur, csr, e);
    k_bounds<<<nb, 256, 0, stream>>>(batch, bnd, n, g);

    // ---- 5 GCN layers: x lives in bufA (fp32), hs in bufH (fp16) ----
    for (int i = 0; i < 5; ++i) {
        const float* xin = (i == 0) ? x0 : bufA;
        const float* bias = (i == 0) ? b0 : bs + (size_t)(i - 1) * HDIM;
        if (i == 0) {
            k_gemm0<<<(n + 1) / 2, 256, 0, stream>>>(x0, W0, dinv, bufH, n, FIN);
        } else {
            const float* W = Ws + (size_t)(i - 1) * HDIM * HDIM;
            k_gemm<<<(n + 63) / 64, 256, 0, stream>>>(bufA, W, dinv, bufH, n);
        }
        k_agg<<<(n + 7) / 8, 256, 0, stream>>>(
            rs, deg, csr, bufH, dinv, bias,
            gam + i * HDIM, bet + i * HDIM, mean + i * HDIM, var + i * HDIM,
            xin, bufA, n, (i > 0) ? 1 : 0);
    }

    // ---- segmented mean pool + head ----
    k_pool_seg<<<(g + 7) / 8, 256, 0, stream>>>(bufA, bnd, pooled, g);
    k_head<<<g, 64, 0, stream>>>(pooled, w1, b1, w2, b2, (float*)d_out);
}